// Round 2
// baseline (760.135 us; speedup 1.0000x reference)
//
#include <hip/hip_runtime.h>

#define N_NODES 50000
#define N_EDGES 800000
#define D_FEAT  128

// ---------------------------------------------------------------------------
// K1: in-degree count via fp32 hardware atomics (deg buffer pre-zeroed).
__global__ void count_deg(const int* __restrict__ dst, float* __restrict__ deg) {
    int e = blockIdx.x * blockDim.x + threadIdx.x;
    if (e < N_EDGES) {
        unsafeAtomicAdd(&deg[dst[e]], 1.0f);
    }
}

// K2: norm[n] = (max(deg,1))^-1/2, in place.
__global__ void make_norm(float* __restrict__ deg) {
    int i = blockIdx.x * blockDim.x + threadIdx.x;
    if (i < N_NODES) {
        float d = deg[i];
        d = d < 1.0f ? 1.0f : d;
        deg[i] = 1.0f / sqrtf(d);
    }
}

// K3: edge-parallel scatter-sum. 128 threads per edge (f = lane offset), so
// the gather h[s*128+f] and atomic acc[d*128+f] are contiguous per edge.
// POW=1: val = h[src]*norm[src]           (hop 1, h = features)
// POW=2: val = h1_raw[src]*norm[src]^2    (hop 2: pre-scale of hop2 fused
//                                          with the un-applied post-scale of hop1)
template<int POW>
__global__ void scatter_hop(const int* __restrict__ src, const int* __restrict__ dst,
                            const float* __restrict__ h, const float* __restrict__ norm,
                            float* __restrict__ acc) {
    int tid = blockIdx.x * blockDim.x + threadIdx.x;  // < 102.4M, fits int32
    int e = tid >> 7;   // tid / 128
    int f = tid & 127;
    if (e < N_EDGES) {
        int s = src[e];
        int d = dst[e];
        float ns = norm[s];
        if (POW == 2) ns *= ns;
        float v = h[s * D_FEAT + f] * ns;
        unsafeAtomicAdd(&acc[d * D_FEAT + f], v);
    }
}

// K4: out = (feat + norm[n]*(h1_raw + h2_raw)) / 3, float4-vectorized.
// d_out currently holds h2_raw (the hop-2 scatter accumulator).
__global__ void finalize(const float4* __restrict__ feat, const float4* __restrict__ h1,
                         const float* __restrict__ norm, float4* __restrict__ out) {
    int i = blockIdx.x * blockDim.x + threadIdx.x;
    const int total = N_NODES * (D_FEAT / 4);
    if (i < total) {
        int n = i >> 5;             // i / (128/4)
        float nn = norm[n];
        float4 f = feat[i];
        float4 a = h1[i];
        float4 b = out[i];
        float4 r;
        const float third = 1.0f / 3.0f;
        r.x = (f.x + nn * (a.x + b.x)) * third;
        r.y = (f.y + nn * (a.y + b.y)) * third;
        r.z = (f.z + nn * (a.z + b.z)) * third;
        r.w = (f.w + nn * (a.w + b.w)) * third;
        out[i] = r;
    }
}

extern "C" void kernel_launch(void* const* d_in, const int* in_sizes, int n_in,
                              void* d_out, int out_size, void* d_ws, size_t ws_size,
                              hipStream_t stream) {
    const float* feat = (const float*)d_in[0];
    const int*   src  = (const int*)d_in[1];
    const int*   dst  = (const int*)d_in[2];
    float* out = (float*)d_out;

    // workspace layout: [norm: 50000 f32, padded to 256KB] [h1_raw: 6.4M f32]
    float* norm = (float*)d_ws;
    float* h1   = (float*)((char*)d_ws + (256 * 1024));

    const size_t h_bytes = (size_t)N_NODES * D_FEAT * sizeof(float);

    // zero accumulators (graph-capture-safe)
    hipMemsetAsync(norm, 0, N_NODES * sizeof(float), stream);
    hipMemsetAsync(h1,   0, h_bytes, stream);
    hipMemsetAsync(out,  0, h_bytes, stream);

    count_deg<<<(N_EDGES + 255) / 256, 256, 0, stream>>>(dst, norm);
    make_norm<<<(N_NODES + 255) / 256, 256, 0, stream>>>(norm);

    // E*D threads total = 102.4M -> 400000 blocks of 256 (was 0 blocks in R0: int-div bug)
    const int scat_blocks = (N_EDGES * (D_FEAT / 4) + 63) / 64;  // == E*128/256
    scatter_hop<1><<<scat_blocks, 256, 0, stream>>>(src, dst, feat, norm, h1);
    scatter_hop<2><<<scat_blocks, 256, 0, stream>>>(src, dst, h1, norm, out);

    const int fin_threads = N_NODES * (D_FEAT / 4);
    finalize<<<(fin_threads + 255) / 256, 256, 0, stream>>>(
        (const float4*)feat, (const float4*)h1, norm, (float4*)out);
}

// Round 3
// 231.540 us; speedup vs baseline: 3.2829x; 3.2829x over previous
//
#include <hip/hip_runtime.h>

#define N_NODES 50000
#define N_EDGES 800000
#define D_FEAT  128
#define SCAN_BLOCKS ((N_NODES + 255) / 256)   // 196

// ---------------------------------------------------------------------------
// K1: histogram of incoming edges per node (cnt pre-zeroed). int atomics.
__global__ void hist_deg(const int* __restrict__ dst, int* __restrict__ cnt) {
    int e = blockIdx.x * blockDim.x + threadIdx.x;
    if (e < N_EDGES) atomicAdd(&cnt[dst[e]], 1);
}

// K2: per-block inclusive scan of cnt -> exclusive offs (block-local),
// block totals to blocksum, and norm[i] = rsqrt(max(cnt,1)) fused here.
__global__ void scan_block(const int* __restrict__ cnt, int* __restrict__ offs,
                           int* __restrict__ blocksum, float* __restrict__ norm) {
    __shared__ int sd[256];
    int tid = threadIdx.x;
    int i = blockIdx.x * 256 + tid;
    int v = (i < N_NODES) ? cnt[i] : 0;
    sd[tid] = v;
    __syncthreads();
    for (int off = 1; off < 256; off <<= 1) {
        int t = (tid >= off) ? sd[tid - off] : 0;
        __syncthreads();
        sd[tid] += t;
        __syncthreads();
    }
    if (i < N_NODES) {
        offs[i] = sd[tid] - v;                       // exclusive, block-local
        float d = (float)(v < 1 ? 1 : v);
        norm[i] = rsqrtf(d);
    }
    if (tid == 255) blocksum[blockIdx.x] = sd[255];
}

// K3: exclusive scan of the 196 block sums (one block).
__global__ void scan_top(int* __restrict__ blocksum) {
    __shared__ int sd[256];
    int tid = threadIdx.x;
    int v = (tid < SCAN_BLOCKS) ? blocksum[tid] : 0;
    sd[tid] = v;
    __syncthreads();
    for (int off = 1; off < 256; off <<= 1) {
        int t = (tid >= off) ? sd[tid - off] : 0;
        __syncthreads();
        sd[tid] += t;
        __syncthreads();
    }
    if (tid < SCAN_BLOCKS) blocksum[tid] = sd[tid] - v;  // exclusive
}

// K4: add block offsets; write the sentinel offs[N] = E.
__global__ void scan_add(int* __restrict__ offs, const int* __restrict__ blocksum) {
    int i = blockIdx.x * 256 + threadIdx.x;
    if (i < N_NODES) offs[i] += blocksum[blockIdx.x];
    if (i == 0) offs[N_NODES] = N_EDGES;
}

// K5: scatter edge sources into CSR slots (cursor pre-zeroed).
__global__ void scatter_e(const int* __restrict__ src, const int* __restrict__ dst,
                          const int* __restrict__ offs, int* __restrict__ cursor,
                          int* __restrict__ eidx) {
    int e = blockIdx.x * blockDim.x + threadIdx.x;
    if (e < N_EDGES) {
        int d = dst[e];
        int pos = atomicAdd(&cursor[d], 1);
        eidx[offs[d] + pos] = src[e];
    }
}

// K6: pull-gather hop. One wave per node; lane holds float2 (cols 2l, 2l+1).
// POW=1: acc += h[s]*norm[s]        (hop 1, h = features)
// POW=2: acc += h1_raw[s]*norm[s]^2 (hop1 post-scale fused with hop2 pre-scale)
// Plain store at the end -> no atomics, no pre-zeroing of the accumulator.
template<int POW>
__global__ void hop_gather(const int* __restrict__ eidx, const int* __restrict__ offs,
                           const float* __restrict__ h, const float* __restrict__ norm,
                           float* __restrict__ acc_out) {
    int node = blockIdx.x * 4 + (threadIdx.x >> 6);   // 4 waves/block, 1 node/wave
    int lane = threadIdx.x & 63;
    const float2* hp = (const float2*)h;
    int b = offs[node];
    int en = offs[node + 1];
    float ax = 0.f, ay = 0.f;
    int i = b;
    for (; i + 1 < en; i += 2) {                      // 2x unroll for load ILP
        int s0 = eidx[i], s1 = eidx[i + 1];
        float n0 = norm[s0], n1 = norm[s1];
        if (POW == 2) { n0 *= n0; n1 *= n1; }
        float2 v0 = hp[s0 * 64 + lane];
        float2 v1 = hp[s1 * 64 + lane];
        ax += v0.x * n0; ay += v0.y * n0;
        ax += v1.x * n1; ay += v1.y * n1;
    }
    if (i < en) {
        int s = eidx[i];
        float ns = norm[s];
        if (POW == 2) ns *= ns;
        float2 v = hp[s * 64 + lane];
        ax += v.x * ns; ay += v.y * ns;
    }
    float2 r; r.x = ax; r.y = ay;
    ((float2*)acc_out)[node * 64 + lane] = r;
}

// K7: out = (feat + norm[n]*(h1_raw + h2_raw)) / 3, float4-vectorized.
__global__ void finalize(const float4* __restrict__ feat, const float4* __restrict__ h1,
                         const float* __restrict__ norm, float4* __restrict__ out) {
    int i = blockIdx.x * blockDim.x + threadIdx.x;
    const int total = N_NODES * (D_FEAT / 4);
    if (i < total) {
        int n = i >> 5;
        float nn = norm[n];
        float4 f = feat[i];
        float4 a = h1[i];
        float4 b = out[i];
        float4 r;
        const float third = 1.0f / 3.0f;
        r.x = (f.x + nn * (a.x + b.x)) * third;
        r.y = (f.y + nn * (a.y + b.y)) * third;
        r.z = (f.z + nn * (a.z + b.z)) * third;
        r.w = (f.w + nn * (a.w + b.w)) * third;
        out[i] = r;
    }
}

extern "C" void kernel_launch(void* const* d_in, const int* in_sizes, int n_in,
                              void* d_out, int out_size, void* d_ws, size_t ws_size,
                              hipStream_t stream) {
    const float* feat = (const float*)d_in[0];
    const int*   src  = (const int*)d_in[1];
    const int*   dst  = (const int*)d_in[2];
    float* out = (float*)d_out;

    // workspace layout (all 256B-aligned):
    char* ws = (char*)d_ws;
    int*   cnt      = (int*)  (ws + 0x000000);   // 50000 i32
    float* norm     = (float*)(ws + 0x040000);   // 50000 f32
    int*   offs     = (int*)  (ws + 0x080000);   // 50001 i32
    int*   cursor   = (int*)  (ws + 0x0C0000);   // 50000 i32
    int*   blocksum = (int*)  (ws + 0x100000);   // 256 i32
    int*   eidx     = (int*)  (ws + 0x110000);   // 800000 i32 (3.2 MB)
    float* h1       = (float*)(ws + 0x450000);   // 6.4M f32 (25.6 MB)

    hipMemsetAsync(cnt,    0, N_NODES * sizeof(int), stream);
    hipMemsetAsync(cursor, 0, N_NODES * sizeof(int), stream);

    // CSR build: histogram -> scan -> scatter
    hist_deg<<<(N_EDGES + 255) / 256, 256, 0, stream>>>(dst, cnt);
    scan_block<<<SCAN_BLOCKS, 256, 0, stream>>>(cnt, offs, blocksum, norm);
    scan_top<<<1, 256, 0, stream>>>(blocksum);
    scan_add<<<SCAN_BLOCKS, 256, 0, stream>>>(offs, blocksum);
    scatter_e<<<(N_EDGES + 255) / 256, 256, 0, stream>>>(src, dst, offs, cursor, eidx);

    // Two pull-gather hops (no fp atomics, accumulators fully overwritten)
    hop_gather<1><<<N_NODES / 4, 256, 0, stream>>>(eidx, offs, feat, norm, h1);
    hop_gather<2><<<N_NODES / 4, 256, 0, stream>>>(eidx, offs, h1, norm, out);

    const int fin_threads = N_NODES * (D_FEAT / 4);
    finalize<<<(fin_threads + 255) / 256, 256, 0, stream>>>(
        (const float4*)feat, (const float4*)h1, norm, (float4*)out);
}

// Round 4
// 213.591 us; speedup vs baseline: 3.5588x; 1.0840x over previous
//
#include <hip/hip_runtime.h>

#define N_NODES 50000
#define N_EDGES 800000
#define D_FEAT  128
#define SCAN_BLOCKS ((N_NODES + 255) / 256)   // 196

// ---------------------------------------------------------------------------
// K1: histogram of incoming edges per node (cnt pre-zeroed). int atomics.
__global__ void hist_deg(const int* __restrict__ dst, int* __restrict__ cnt) {
    int e = blockIdx.x * blockDim.x + threadIdx.x;
    if (e < N_EDGES) atomicAdd(&cnt[dst[e]], 1);
}

// K2: per-block inclusive scan of cnt -> exclusive offs (block-local),
// block totals to blocksum, and norm[i] = rsqrt(max(cnt,1)) fused here.
__global__ void scan_block(const int* __restrict__ cnt, int* __restrict__ offs,
                           int* __restrict__ blocksum, float* __restrict__ norm) {
    __shared__ int sd[256];
    int tid = threadIdx.x;
    int i = blockIdx.x * 256 + tid;
    int v = (i < N_NODES) ? cnt[i] : 0;
    sd[tid] = v;
    __syncthreads();
    for (int off = 1; off < 256; off <<= 1) {
        int t = (tid >= off) ? sd[tid - off] : 0;
        __syncthreads();
        sd[tid] += t;
        __syncthreads();
    }
    if (i < N_NODES) {
        offs[i] = sd[tid] - v;                       // exclusive, block-local
        float d = (float)(v < 1 ? 1 : v);
        norm[i] = rsqrtf(d);
    }
    if (tid == 255) blocksum[blockIdx.x] = sd[255];
}

// K3: add block prefix (each block sums blocksum[0..b-1] itself — 196 ints,
// L2-hot, cheaper than a separate scan_top kernel + launch gap).
__global__ void scan_add(int* __restrict__ offs, const int* __restrict__ blocksum) {
    __shared__ int prefix_s;
    int tid = threadIdx.x;
    if (tid < 64) {
        int p = 0;
        for (int j = tid; j < blockIdx.x; j += 64) p += blocksum[j];
        for (int o = 32; o; o >>= 1) p += __shfl_down(p, o, 64);
        if (tid == 0) prefix_s = p;
    }
    __syncthreads();
    int i = blockIdx.x * 256 + tid;
    if (i < N_NODES) offs[i] += prefix_s;
    if (blockIdx.x == 0 && tid == 0) offs[N_NODES] = N_EDGES;
}

// K4: scatter edge sources into CSR slots (cursor pre-zeroed).
__global__ void scatter_e(const int* __restrict__ src, const int* __restrict__ dst,
                          const int* __restrict__ offs, int* __restrict__ cursor,
                          int* __restrict__ eidx) {
    int e = blockIdx.x * blockDim.x + threadIdx.x;
    if (e < N_EDGES) {
        int d = dst[e];
        int pos = atomicAdd(&cursor[d], 1);
        eidx[offs[d] + pos] = src[e];
    }
}

// K5: pull-gather hop. One wave per node. Dual-edge float4 layout:
//   lane = 32*half + l32; half-wave 0 processes edge i, half-wave 1 edge i+1,
//   each lane loads float4 (cols 4*l32..4*l32+3) -> one dwordx4 instruction
//   covers 1024B / 2 edges. 4 edges in flight per loop iter.
// POW=1: acc += h[s]*norm[s]        (hop 1, h = features)
// POW=2: acc += h1_raw[s]*norm[s]^2 (hop1 post-scale fused with hop2 pre-scale)
// FINAL=1: fuse layer-mean: out = (feat + norm[node]*(h1_raw + acc)) / 3.
template<int POW, int FINAL>
__global__ void hop_gather(const int* __restrict__ eidx, const int* __restrict__ offs,
                           const float* __restrict__ h, const float* __restrict__ norm,
                           const float* __restrict__ feat, const float* __restrict__ h1,
                           float* __restrict__ out) {
    int node = blockIdx.x * 4 + (threadIdx.x >> 6);   // 4 waves/block, 1 node/wave
    int lane = threadIdx.x & 63;
    int half = lane >> 5;
    int l32  = lane & 31;
    const float4* hp = (const float4*)h;
    int b  = offs[node];
    int en = offs[node + 1];
    int ecnt = en - b;
    float ax = 0.f, ay = 0.f, az = 0.f, aw = 0.f;
    int i = 0;
    for (; i + 4 <= ecnt; i += 4) {                   // 4 edges per iter
        int sA = eidx[b + i + half];
        int sB = eidx[b + i + 2 + half];
        float nA = norm[sA], nB = norm[sB];
        if (POW == 2) { nA *= nA; nB *= nB; }
        float4 vA = hp[sA * 32 + l32];
        float4 vB = hp[sB * 32 + l32];
        ax += vA.x * nA + vB.x * nB;
        ay += vA.y * nA + vB.y * nB;
        az += vA.z * nA + vB.z * nB;
        aw += vA.w * nA + vB.w * nB;
    }
    if (i + 2 <= ecnt) {                              // 2-edge tail
        int s = eidx[b + i + half];
        float n = norm[s];
        if (POW == 2) n *= n;
        float4 v = hp[s * 32 + l32];
        ax += v.x * n; ay += v.y * n; az += v.z * n; aw += v.w * n;
        i += 2;
    }
    if (i < ecnt && half == 0) {                      // 1-edge tail (half 0 only)
        int s = eidx[b + i];
        float n = norm[s];
        if (POW == 2) n *= n;
        float4 v = hp[s * 32 + l32];
        ax += v.x * n; ay += v.y * n; az += v.z * n; aw += v.w * n;
    }
    // combine the two half-wave partial sums (same columns, different edges)
    ax += __shfl_xor(ax, 32, 64);
    ay += __shfl_xor(ay, 32, 64);
    az += __shfl_xor(az, 32, 64);
    aw += __shfl_xor(aw, 32, 64);
    if (half == 0) {
        float4 r;
        if (FINAL) {
            float nn = norm[node];
            float4 f = ((const float4*)feat)[node * 32 + l32];
            float4 p = ((const float4*)h1)[node * 32 + l32];
            const float third = 1.0f / 3.0f;
            r.x = (f.x + nn * (p.x + ax)) * third;
            r.y = (f.y + nn * (p.y + ay)) * third;
            r.z = (f.z + nn * (p.z + az)) * third;
            r.w = (f.w + nn * (p.w + aw)) * third;
        } else {
            r.x = ax; r.y = ay; r.z = az; r.w = aw;
        }
        ((float4*)out)[node * 32 + l32] = r;
    }
}

extern "C" void kernel_launch(void* const* d_in, const int* in_sizes, int n_in,
                              void* d_out, int out_size, void* d_ws, size_t ws_size,
                              hipStream_t stream) {
    const float* feat = (const float*)d_in[0];
    const int*   src  = (const int*)d_in[1];
    const int*   dst  = (const int*)d_in[2];
    float* out = (float*)d_out;

    // workspace layout (cnt and cursor in the first 512KB -> single memset):
    char* ws = (char*)d_ws;
    int*   cnt      = (int*)  (ws + 0x000000);   // 50000 i32
    int*   cursor   = (int*)  (ws + 0x040000);   // 50000 i32
    float* norm     = (float*)(ws + 0x080000);   // 50000 f32
    int*   offs     = (int*)  (ws + 0x0C0000);   // 50001 i32
    int*   blocksum = (int*)  (ws + 0x100000);   // 196 i32
    int*   eidx     = (int*)  (ws + 0x110000);   // 800000 i32 (3.2 MB)
    float* h1       = (float*)(ws + 0x450000);   // 6.4M f32 (25.6 MB)

    hipMemsetAsync(ws, 0, 0x80000, stream);      // cnt + cursor

    // CSR build: histogram -> scan -> scatter
    hist_deg<<<(N_EDGES + 255) / 256, 256, 0, stream>>>(dst, cnt);
    scan_block<<<SCAN_BLOCKS, 256, 0, stream>>>(cnt, offs, blocksum, norm);
    scan_add<<<SCAN_BLOCKS, 256, 0, stream>>>(offs, blocksum);
    scatter_e<<<(N_EDGES + 255) / 256, 256, 0, stream>>>(src, dst, offs, cursor, eidx);

    // hop 1 (h = feat -> h1), hop 2 fused with layer-mean finalize (-> out)
    hop_gather<1, 0><<<N_NODES / 4, 256, 0, stream>>>(eidx, offs, feat, norm,
                                                      nullptr, nullptr, h1);
    hop_gather<2, 1><<<N_NODES / 4, 256, 0, stream>>>(eidx, offs, h1, norm,
                                                      feat, h1, out);
}